// Round 3
// baseline (781.559 us; speedup 1.0000x reference)
//
#include <hip/hip_runtime.h>
#include <hip/hip_bf16.h>
#include <cstddef>
#include <cstdint>

#define BB   32
#define TT   2048
#define DIN  512
#define DD   512
#define NN   3072
#define PROJW 4096   // f16 gate row: col = d*8 + k; k=0..5 used (a0,a1,t2,a3,a4,z5), 6,7 pad
#define PF   8       // scan prefetch depth (steps)

typedef __attribute__((ext_vector_type(4))) float f32x4;
typedef __attribute__((ext_vector_type(8))) short s16x8;
typedef _Float16 f16x8 __attribute__((ext_vector_type(8)));

// ---------------------------------------------------------------------------
// helpers
// ---------------------------------------------------------------------------
__device__ __forceinline__ void gl2lds16(const void* g, void* l) {
    __builtin_amdgcn_global_load_lds(
        (const __attribute__((address_space(1))) unsigned*)g,
        (__attribute__((address_space(3))) unsigned*)l, 16, 0, 0);
}

__device__ __forceinline__ unsigned short bfr(float f) {   // f32 -> bf16 RNE
    unsigned u = __float_as_uint(f);
    u += 0x7fffu + ((u >> 16) & 1u);
    return (unsigned short)(u >> 16);
}

__device__ __forceinline__ float ftanh(float x) {
    // tanh(x) = 1 - 2/(1+e^{2x}); exp2 arg = 2x*log2(e)
    return 1.f - 2.f * __builtin_amdgcn_rcpf(1.f + __builtin_amdgcn_exp2f(x * 2.885390082f));
}

// ---------------------------------------------------------------------------
// convert x [B][T][DIN] f32 -> x2 [(t*32+b)][DIN] bf16   (GEMM row = t*B+b)
// ---------------------------------------------------------------------------
__global__ __launch_bounds__(256) void convert_x(
    const float* __restrict__ x, unsigned short* __restrict__ x2)
{
    const int total4 = BB * TT * DIN / 4;
    for (int idx = blockIdx.x * 256 + threadIdx.x; idx < total4;
         idx += gridDim.x * 256) {
        int e = idx * 4;
        int b = e >> 20;
        int t = (e >> 9) & 2047;
        int i = e & 511;
        float4 v = *(const float4*)(x + (size_t)e);
        ushort4 o;
        o.x = bfr(v.x); o.y = bfr(v.y); o.z = bfr(v.z); o.w = bfr(v.w);
        *(ushort4*)(x2 + ((size_t)((t << 5) | b) << 9) + i) = o;
    }
}

// ---------------------------------------------------------------------------
// convert W: W2 row c corresponds to gate-interleaved col c = d*6+k,
// i.e. original W row o = k*512 + d. bias permuted likewise.
// ---------------------------------------------------------------------------
__global__ __launch_bounds__(128) void convert_w(
    const float* __restrict__ W, const float* __restrict__ bias,
    unsigned short* __restrict__ W2, float* __restrict__ bias2)
{
    int c = blockIdx.x;            // 0..3071, = d*6+k
    int d = c / 6, k = c - d * 6;
    int o = (k << 9) + d;
    const float* src = W + (size_t)o * DIN;
    unsigned short* dst = W2 + (size_t)c * DIN;
    int i = threadIdx.x * 4;
    float4 v = *(const float4*)(src + i);
    ushort4 u;
    u.x = bfr(v.x); u.y = bfr(v.y); u.z = bfr(v.z); u.w = bfr(v.w);
    *(ushort4*)(dst + i) = u;
    if (threadIdx.x == 0) bias2[c] = bias[o];
}

// ---------------------------------------------------------------------------
// bf16 MFMA GEMM + fused gate activation epilogue.
// 128x128 tile, BK=64, 4 waves (2x2), 16x16x32 MFMA, global_load_lds w=16.
// GEMM col c = d*6+k (W2 pre-permuted). Epilogue: z = acc + bias;
//   k in {0,1,3,4} -> sigmoid(z); k==2 -> tanh(z); k==5 -> z.
// Stored f16 at scol = d*8+k.
// ---------------------------------------------------------------------------
__global__ __launch_bounds__(256) void gemm_proj(
    const unsigned short* __restrict__ x2,    // [T*32][512]
    const unsigned short* __restrict__ W2,    // [3072][512]
    const float* __restrict__ bias2,          // [3072]
    _Float16* __restrict__ proj,              // [Mc][PROJW]
    int t0)
{
    __shared__ unsigned short As[128][64];
    __shared__ unsigned short Bs[128][64];

    const int tid  = threadIdx.x;
    const int lane = tid & 63;
    const int w    = tid >> 6;
    const int wr   = w >> 1, wc = w & 1;
    const int lr   = lane & 15, lq = lane >> 4;

    // XCD-aware bijective swizzle of the flat workgroup id (nwg % 8 == 0)
    const unsigned nwgx = gridDim.x;                    // 24 col-tiles
    const unsigned nwg  = nwgx * gridDim.y;
    unsigned f   = blockIdx.y * nwgx + blockIdx.x;
    unsigned swz = (f & 7u) * (nwg >> 3) + (f >> 3);
    const int bx = (int)(swz % nwgx);
    const int by = (int)(swz / nwgx);

    const int row0 = by * 128;                // chunk-local proj row
    const int col0 = bx * 128;
    const size_t growA = (size_t)t0 * BB + row0;   // global x2 row

    f32x4 acc[4][4] = {};

    for (int k0 = 0; k0 < DIN; k0 += 64) {
        #pragma unroll
        for (int i = 0; i < 4; ++i) {
            int c  = tid + i * 256;
            int r  = c >> 3;
            int kc = (c & 7) * 8;
            gl2lds16(x2 + (growA + r) * DIN + k0 + kc, &As[r][kc]);
            gl2lds16(W2 + (size_t)(col0 + r) * DIN + k0 + kc, &Bs[r][kc]);
        }
        __syncthreads();

        #pragma unroll
        for (int kk = 0; kk < 64; kk += 32) {
            s16x8 av[4], bv[4];
            #pragma unroll
            for (int i = 0; i < 4; ++i)
                av[i] = *(const s16x8*)&As[wr * 64 + i * 16 + lr][kk + lq * 8];
            #pragma unroll
            for (int j = 0; j < 4; ++j)
                bv[j] = *(const s16x8*)&Bs[wc * 64 + j * 16 + lr][kk + lq * 8];
            #pragma unroll
            for (int i = 0; i < 4; ++i)
                #pragma unroll
                for (int j = 0; j < 4; ++j)
                    acc[i][j] = __builtin_amdgcn_mfma_f32_16x16x32_bf16(
                        av[i], bv[j], acc[i][j], 0, 0, 0);
        }
        __syncthreads();
    }

    // Epilogue: bias + per-gate activation + f16 store (gate-interleaved)
    #pragma unroll
    for (int j = 0; j < 4; ++j) {
        int col  = col0 + wc * 64 + j * 16 + lr;          // 0..3071 = d*6+k
        int dcol = (int)(((unsigned)col * 43691u) >> 18); // col/6 exact
        int k    = col - 6 * dcol;
        int scol = (dcol << 3) + k;                       // d*8+k
        float bc = bias2[col];
        const bool  isT = (k == 2);
        const bool  isI = (k == 5);
        const float m   = isT ? 2.885390082f : -1.442695041f;
        #pragma unroll
        for (int i = 0; i < 4; ++i) {
            int rbase = row0 + wr * 64 + i * 16 + lq * 4;
            #pragma unroll
            for (int r = 0; r < 4; ++r) {
                float z  = acc[i][j][r] + bc;
                float e  = __builtin_amdgcn_exp2f(z * m);
                float rr = __builtin_amdgcn_rcpf(1.f + e);
                float v  = isT ? (1.f - 2.f * rr) : rr;   // tanh vs sigmoid
                if (isI) v = z;                           // k==5: identity
                proj[(size_t)(rbase + r) * PROJW + scol] = (_Float16)v;
            }
        }
    }
}

// ---------------------------------------------------------------------------
// Scan: one thread per (b,d). Gates pre-activated; per step only ONE
// state-dependent tanh remains on the critical path.
//   s = a0*s + a1*t2 ;  h = a3*h + a4*tanh(z5 + s)
// ---------------------------------------------------------------------------
__global__ __launch_bounds__(64) void scan_chunk(
    const _Float16* __restrict__ proj,   // [Tc*32][PROJW]
    const float* __restrict__ h0, const float* __restrict__ s0,
    float* __restrict__ outH, float* __restrict__ outS,
    int t0, int Tc)
{
    const int gid = blockIdx.x * 64 + threadIdx.x;   // 0..16383
    const int b   = gid >> 9;
    const int d   = gid & 511;

    float h, s;
    if (t0 == 0) { h = h0[gid]; s = s0[gid]; }
    else {
        h = outH[((size_t)b * TT + (t0 - 1)) * DD + d];
        s = outS[gid];
    }

    const f16x8* pbase = (const f16x8*)(proj + (size_t)b * PROJW + d * 8);
    const size_t tstride = ((size_t)BB * PROJW) / 8;  // f16x8 units per step
    float* oH = outH + ((size_t)b * TT + t0) * DD + d;

    f16x8 bufA[PF], bufB[PF];

    #pragma unroll
    for (int u = 0; u < PF; ++u) bufA[u] = pbase[(size_t)u * tstride];

    for (int tb = 0; tb < Tc; tb += 2 * PF) {
        #pragma unroll
        for (int u = 0; u < PF; ++u) {
            int t = tb + PF + u; if (t > Tc - 1) t = Tc - 1;
            bufB[u] = pbase[(size_t)t * tstride];
        }
        #pragma unroll
        for (int u = 0; u < PF; ++u) {
            f16x8 g = bufA[u];
            float a0 = (float)g[0], a1 = (float)g[1], t2 = (float)g[2];
            float a3 = (float)g[3], a4 = (float)g[4], z5 = (float)g[5];
            s = __builtin_fmaf(a0, s, a1 * t2);
            h = __builtin_fmaf(a3, h, a4 * ftanh(z5 + s));
            oH[(size_t)(tb + u) * DD] = h;
        }
        #pragma unroll
        for (int u = 0; u < PF; ++u) {
            int t = tb + 2 * PF + u; if (t > Tc - 1) t = Tc - 1;
            bufA[u] = pbase[(size_t)t * tstride];
        }
        #pragma unroll
        for (int u = 0; u < PF; ++u) {
            f16x8 g = bufB[u];
            float a0 = (float)g[0], a1 = (float)g[1], t2 = (float)g[2];
            float a3 = (float)g[3], a4 = (float)g[4], z5 = (float)g[5];
            s = __builtin_fmaf(a0, s, a1 * t2);
            h = __builtin_fmaf(a3, h, a4 * ftanh(z5 + s));
            oH[(size_t)(tb + PF + u) * DD] = h;
        }
    }

    outS[gid] = s;
}

// ---------------------------------------------------------------------------
extern "C" void kernel_launch(void* const* d_in, const int* in_sizes, int n_in,
                              void* d_out, int out_size, void* d_ws, size_t ws_size,
                              hipStream_t stream) {
    const float* x    = (const float*)d_in[0];
    const float* h0   = (const float*)d_in[1];
    const float* s0   = (const float*)d_in[2];
    const float* W    = (const float*)d_in[3];
    const float* bias = (const float*)d_in[4];

    float* outH = (float*)d_out;
    float* outS = outH + (size_t)BB * TT * DD;

    char* ws = (char*)d_ws;
    const size_t x2_bytes = (size_t)BB * TT * DIN * 2;       // 64 MB
    const size_t w2_bytes = (size_t)NN * DIN * 2;            // 3 MB
    const size_t b2_bytes = (size_t)NN * 4;
    unsigned short* x2    = (unsigned short*)ws;
    unsigned short* W2    = (unsigned short*)(ws + x2_bytes);
    float*          bias2 = (float*)(ws + x2_bytes + w2_bytes);
    _Float16*       proj  = (_Float16*)(ws + x2_bytes + w2_bytes + b2_bytes);

    const size_t fixed = x2_bytes + w2_bytes + b2_bytes;
    const size_t per_t = (size_t)BB * PROJW * 2;             // 262144 B
    int TcMax = (int)((ws_size > fixed ? ws_size - fixed : 0) / per_t);
    if (TcMax > 512) TcMax = 512;   // keep proj chunk L3-resident
    TcMax &= ~15;                   // multiple of 16 (2*PF, and of 4 for grid)
    if (TcMax < 16) TcMax = 16;

    convert_x<<<2048, 256, 0, stream>>>(x, x2);
    convert_w<<<NN, 128, 0, stream>>>(W, bias, W2, bias2);

    for (int t0 = 0; t0 < TT; t0 += TcMax) {
        int Tc = TT - t0;
        if (Tc > TcMax) Tc = TcMax;
        dim3 ggrid(NN / 128, Tc * BB / 128);
        gemm_proj<<<ggrid, 256, 0, stream>>>(x2, W2, bias2, proj, t0);
        scan_chunk<<<(BB * DD) / 64, 64, 0, stream>>>(proj, h0, s0, outH, outS, t0, Tc);
    }
}